// Round 8
// baseline (748.415 us; speedup 1.0000x reference)
//
#include <hip/hip_runtime.h>
#include <hip/hip_bf16.h>

#define T_DIM 1024
#define B_DIM 16
#define H_DIM 1024
#define L_DIM 3
#define M_DIM (T_DIM * B_DIM)
#define N_DIM (3 * H_DIM)
#define K_DIM H_DIM
#define NC 64
#define CS 16

typedef __bf16 bf16x8 __attribute__((ext_vector_type(8)));
typedef __bf16 bf16x4 __attribute__((ext_vector_type(4)));
typedef _Float16 half4 __attribute__((ext_vector_type(4)));
typedef float f32x4 __attribute__((ext_vector_type(4)));

__device__ __forceinline__ __bf16 f2bf(float f) {
    return (__bf16)__float2bfloat16(f);
}

__device__ __forceinline__ void async_cp16(const void* g, void* lds) {
    __builtin_amdgcn_global_load_lds(
        (__attribute__((address_space(1))) void*)g,
        (__attribute__((address_space(3))) void*)lds, 16, 0, 0);
}

// ---------- fused prep: W transpose+cast (blocks 0..9215) + embed gather (rest) ----------
#define TW_BLOCKS (32 * 96 * 3)
__global__ void prep_kernel(const float* __restrict__ W, __bf16* __restrict__ Wt,
                            const int* __restrict__ x, const float4* __restrict__ emb,
                            __bf16* __restrict__ h) {
    if (blockIdx.x < TW_BLOCKS) {
        __shared__ __bf16 tile[32][33];
        const int blk = blockIdx.x;
        const int l = blk / 3072;
        const int r2 = blk % 3072;
        const int n0 = (r2 / 32) * 32, k0 = (r2 % 32) * 32;
        const int tx = threadIdx.x & 31, ty = threadIdx.x >> 5;
        const float* Wl = W + (size_t)l * K_DIM * N_DIM;
        __bf16* Wtl = Wt + (size_t)l * N_DIM * K_DIM;
#pragma unroll
        for (int q = 0; q < 4; q++) {
            int k = ty + q * 8;
            tile[k][tx] = f2bf(Wl[(size_t)(k0 + k) * N_DIM + n0 + tx]);
        }
        __syncthreads();
#pragma unroll
        for (int q = 0; q < 4; q++) {
            int n = ty + q * 8;
            Wtl[(size_t)(n0 + n) * K_DIM + k0 + tx] = tile[tx][n];
        }
    } else {
        int i = (blockIdx.x - TW_BLOCKS) * 256 + threadIdx.x;
        int row = i >> 8;
        int j = i & 255;
        int idx = x[row];
        float4 v = emb[(size_t)idx * 256 + j];
        __bf16* dst = h + (size_t)row * H_DIM + j * 4;
        dst[0] = f2bf(v.x); dst[1] = f2bf(v.y); dst[2] = f2bf(v.z); dst[3] = f2bf(v.w);
    }
}

// ---------- GEMM + bias + activation -> fp16 planar gates ----------
// v3 + nt-stores (R8): counted-vmcnt depth-2 pipeline, unchanged K-loop.
// 128x256 tile, 8 waves (2M x 4N) of 64x64, K-step 32.
// LDS: 3-region ring As[3][128][32] + Bs[3][256][32] = 72 KiB -> 2 blocks/CU.
// Per step: wait vmcnt(3), barrier, ds_read frags, STAGE(t+2), MFMA. No vmcnt(0) in loop.
// Epilogue gate stores are NON-TEMPORAL: 96 MB of gate writes were thrashing L2 and
// evicting the A/B staging panels (FETCH_SIZE 110-142 MB vs ~38 MB ideal).
__global__ __launch_bounds__(512, 4) void gemm_gates(
    const __bf16* __restrict__ A,
    const __bf16* __restrict__ Wt,
    const float* __restrict__ bias,
    _Float16* __restrict__ Gz, _Float16* __restrict__ Gf, _Float16* __restrict__ Go) {
    __shared__ __align__(16) __bf16 As[3 * 4096];   // [region][128 rows][32 k]
    __shared__ __align__(16) __bf16 Bs[3 * 8192];   // [region][256 rows][32 k]

    const int tid = threadIdx.x;
    const int lane = tid & 63, wid = tid >> 6;
    const int lm = lane & 15, kg = lane >> 4;
    const int wm = wid >> 2, wn = wid & 3;          // 2M x 4N waves of 64x64

    // XCD-bijective swizzle: 1536 blocks, 192/XCD, bm-major chunks (16 bm-panels x 12 bn).
    const int orig = blockIdx.x;                    // 0..1535
    const int lin = (orig & 7) * 192 + (orig >> 3);
    const int bm = lin / 12, bn = lin % 12;

    // staging: A-tile 128x32 (1 load/thread), B-tile 256x32 (2 loads/thread)
    const int arow = tid >> 2;                      // 0..127
    const int asch = (tid & 3) ^ ((arow >> 1) & 3);
    const int gaA = arow * K_DIM + asch * 8;
    const int loA = tid * 8;
    const int brow0 = tid >> 2, brow1 = (512 + tid) >> 2;
    const int bsch0 = (tid & 3) ^ ((brow0 >> 1) & 3);
    const int bsch1 = (tid & 3) ^ ((brow1 >> 1) & 3);
    const int gaB0 = brow0 * K_DIM + bsch0 * 8;
    const int gaB1 = brow1 * K_DIM + bsch1 * 8;
    const int loB0 = tid * 8;
    const int loB1 = (512 + tid) * 8;

    const __bf16* Abase = A + (size_t)(bm * 128) * K_DIM;
    const __bf16* Bbase = Wt + (size_t)(bn * 256) * K_DIM;

    // ds_read fragment offsets (within one region)
    const int slot8 = (kg ^ ((lm >> 1) & 3)) * 8;
    const int a_off0 = (wm * 64 + 0 * 16 + lm) * 32 + slot8;
    const int a_off1 = (wm * 64 + 1 * 16 + lm) * 32 + slot8;
    const int a_off2 = (wm * 64 + 2 * 16 + lm) * 32 + slot8;
    const int a_off3 = (wm * 64 + 3 * 16 + lm) * 32 + slot8;
    const int b_off0 = (wn * 64 + 0 * 16 + lm) * 32 + slot8;
    const int b_off1 = (wn * 64 + 1 * 16 + lm) * 32 + slot8;
    const int b_off2 = (wn * 64 + 2 * 16 + lm) * 32 + slot8;
    const int b_off3 = (wn * 64 + 3 * 16 + lm) * 32 + slot8;

    f32x4 acc[4][4] = {};

#define STAGE(TN) { \
    const int kc_ = ((TN) & 31) * 32; \
    const int rg_ = (TN) % 3; \
    async_cp16(Abase + kc_ + gaA, As + rg_ * 4096 + loA); \
    async_cp16(Bbase + kc_ + gaB0, Bs + rg_ * 8192 + loB0); \
    async_cp16(Bbase + kc_ + gaB1, Bs + rg_ * 8192 + loB1); }

    // prologue: stage tiles 0 and 1 (6 loads outstanding; never drained to 0 in the loop)
    STAGE(0)
    STAGE(1)

#pragma unroll 1
    for (int t = 0; t < 32; ++t) {
        // oldest 3 loads = tile t's stage -> region t%3 ready once ALL waves pass this
        asm volatile("s_waitcnt vmcnt(3)" ::: "memory");
        __builtin_amdgcn_s_barrier();
        __builtin_amdgcn_sched_barrier(0);
        const int rg = t % 3;
        const __bf16* rA = As + rg * 4096;
        const __bf16* rB = Bs + rg * 8192;
        bf16x8 bf0 = *(const bf16x8*)(rB + b_off0);
        bf16x8 bf1 = *(const bf16x8*)(rB + b_off1);
        bf16x8 bf2 = *(const bf16x8*)(rB + b_off2);
        bf16x8 bf3 = *(const bf16x8*)(rB + b_off3);
        bf16x8 af0 = *(const bf16x8*)(rA + a_off0);
        bf16x8 af1 = *(const bf16x8*)(rA + a_off1);
        bf16x8 af2 = *(const bf16x8*)(rA + a_off2);
        bf16x8 af3 = *(const bf16x8*)(rA + a_off3);
        STAGE(t + 2)   // t>=30 wraps to tiles 0/1 (regions differ from t%3,(t+1)%3: safe)
        __builtin_amdgcn_s_setprio(1);
#define MFJ(I, AF) \
        acc[I][0] = __builtin_amdgcn_mfma_f32_16x16x32_bf16(AF, bf0, acc[I][0], 0, 0, 0); \
        acc[I][1] = __builtin_amdgcn_mfma_f32_16x16x32_bf16(AF, bf1, acc[I][1], 0, 0, 0); \
        acc[I][2] = __builtin_amdgcn_mfma_f32_16x16x32_bf16(AF, bf2, acc[I][2], 0, 0, 0); \
        acc[I][3] = __builtin_amdgcn_mfma_f32_16x16x32_bf16(AF, bf3, acc[I][3], 0, 0, 0);
        MFJ(0, af0) MFJ(1, af1) MFJ(2, af2) MFJ(3, af3)
#undef MFJ
        __builtin_amdgcn_s_setprio(0);
    }
    asm volatile("s_waitcnt vmcnt(0)" ::: "memory");

#undef STAGE

    // epilogue; plane is block-uniform (bn covers 256 cols inside one 1024-col plane)
    const int plane = bn >> 2;
    _Float16* __restrict__ P = (plane == 0) ? Gz : (plane == 1) ? Gf : Go;
    const int colbase = (bn & 3) * 256 + wn * 64;
    const int nb = bn * 256 + wn * 64;
#pragma unroll
    for (int i = 0; i < 4; i++) {
#pragma unroll
        for (int j = 0; j < 4; j++) {
            int col = colbase + j * 16 + lm;
            float bv = bias[nb + j * 16 + lm];
#pragma unroll
            for (int r = 0; r < 4; r++) {
                int mrow = bm * 128 + wm * 64 + i * 16 + kg * 4 + r;
                float g = acc[i][j][r] + bv;
                float val;
                if (plane == 0) {
                    // tanh(g) = sign(g) * (1 - 2e/(1+e)), e = exp(-2|g|) <= 1
                    float e = __expf(-2.0f * fabsf(g));
                    float rc = __builtin_amdgcn_rcpf(1.0f + e);
                    val = copysignf(fmaf(-2.0f * e, rc, 1.0f), g);
                } else {
                    float e = __expf(-g);
                    val = __builtin_amdgcn_rcpf(1.0f + e);
                }
                // non-temporal: gates are consumed by the scan kernels, not re-read here;
                // keep them out of L2 so A/B staging panels stay resident.
                __builtin_nontemporal_store((_Float16)val, &P[(size_t)mrow * H_DIM + col]);
            }
        }
    }
}

// ---------- pass 1: per-chunk affine aggregates ----------
__global__ __launch_bounds__(256, 8) void scan_pass1(
    const _Float16* __restrict__ Gz, const _Float16* __restrict__ Gf,
    float* __restrict__ cA, float* __restrict__ cM) {
    int tidg = blockIdx.x * 256 + threadIdx.x;   // 262144
    int ci = tidg >> 12;
    int chg = tidg & 4095;
    size_t base = (size_t)(ci * CS) * 16384 + (size_t)chg * 4;
    f32x4 Aacc = {0.f, 0.f, 0.f, 0.f};
    f32x4 Macc = {1.f, 1.f, 1.f, 1.f};
#pragma unroll
    for (int s = 0; s < CS; s++) {
        half4 z = *(const half4*)(Gz + base);
        half4 f = *(const half4*)(Gf + base);
#pragma unroll
        for (int k = 0; k < 4; k++) {
            float fk = (float)f[k], zk = (float)z[k];
            Aacc[k] = fk * zk + (1.f - fk) * Aacc[k];
            Macc[k] = (1.f - fk) * Macc[k];
        }
        base += 16384;
    }
    size_t idx = (size_t)ci * 16384 + (size_t)chg * 4;
    *(f32x4*)(cA + idx) = Aacc;
    *(f32x4*)(cM + idx) = Macc;
}

// ---------- pass 1.5: sequential chunk-prefix scan, in-place into cM ----------
// One thread per channel-group (4096 threads). Same fold expression, same cj order as the
// old redundant per-block fold -> bit-identical values. After this kernel,
// cM[cj] holds the running state c ENTERING chunk cj+1 (i.e. prefix over chunks 0..cj).
__global__ __launch_bounds__(256, 8) void scan_prefix(
    const float* __restrict__ cA, float* __restrict__ cM) {
    int chg = blockIdx.x * 256 + threadIdx.x;    // 0..4095
    size_t off = (size_t)chg * 4;
    f32x4 c = {0.f, 0.f, 0.f, 0.f};
#pragma unroll 4
    for (int cj = 0; cj < NC - 1; cj++) {
        f32x4 a = *(const f32x4*)(cA + (size_t)cj * 16384 + off);
        f32x4 m = *(const f32x4*)(cM + (size_t)cj * 16384 + off);
#pragma unroll
        for (int k = 0; k < 4; k++) c[k] = a[k] + m[k] * c[k];
        *(f32x4*)(cM + (size_t)cj * 16384 + off) = c;
    }
}

// ---------- pass 2+3: load chunk-prefix + rescan + o-gate ----------
// nt loads: last use of the gate data (don't allocate dying lines in L2).
// nt store for the final f32 output (never re-read). hbuf store stays normal
// (it is the NEXT layer's A operand and wants to be cache-resident).
__global__ __launch_bounds__(256, 8) void scan_pass23(
    const _Float16* __restrict__ Gz, const _Float16* __restrict__ Gf,
    const _Float16* __restrict__ Go,
    const float* __restrict__ cM,
    __bf16* __restrict__ hdst, float* __restrict__ fdst, int is_last) {
    int tidg = blockIdx.x * 256 + threadIdx.x;   // 262144
    int ci = tidg >> 12;                         // uniform per block
    int chg = tidg & 4095;
    // incoming state for this chunk = prefix over chunks 0..ci-1 (precomputed by scan_prefix)
    f32x4 c = {0.f, 0.f, 0.f, 0.f};
    if (ci > 0)
        c = *(const f32x4*)(cM + (size_t)(ci - 1) * 16384 + (size_t)chg * 4);
    size_t p = (size_t)(ci * CS) * 16384 + (size_t)chg * 4;
#pragma unroll
    for (int s = 0; s < CS; s++) {
        int t = ci * CS + s;
        half4 z = __builtin_nontemporal_load((const half4*)(Gz + p));
        half4 f = __builtin_nontemporal_load((const half4*)(Gf + p));
        half4 o = __builtin_nontemporal_load((const half4*)(Go + p));
        f32x4 val;
#pragma unroll
        for (int k = 0; k < 4; k++) {
            float fk = (float)f[k];
            c[k] = fk * (float)z[k] + (1.f - fk) * c[k];
            val[k] = (float)o[k] * c[k];
        }
        if (is_last) {
            if (t < T_DIM - 1)
                __builtin_nontemporal_store(val, (f32x4*)(fdst + p));
        } else {
            bf16x4 hv;
#pragma unroll
            for (int k = 0; k < 4; k++) hv[k] = f2bf(val[k]);
            *(bf16x4*)(hdst + p) = hv;
        }
        p += 16384;
    }
}

extern "C" void kernel_launch(void* const* d_in, const int* in_sizes, int n_in,
                              void* d_out, int out_size, void* d_ws, size_t ws_size,
                              hipStream_t stream) {
    const int* x = (const int*)d_in[0];
    const float* emb = (const float*)d_in[1];
    const float* W = (const float*)d_in[2];
    const float* b = (const float*)d_in[3];
    float* out = (float*)d_out;

    char* ws = (char*)d_ws;
    size_t need = (size_t)L_DIM * N_DIM * K_DIM * 2
                + (size_t)M_DIM * H_DIM * 2
                + 3ull * M_DIM * H_DIM * 2
                + 2ull * NC * 16384 * 4;
    if (ws_size < need) return;

    __bf16* Wt = (__bf16*)ws;     ws += (size_t)L_DIM * N_DIM * K_DIM * 2;
    __bf16* hbuf = (__bf16*)ws;   ws += (size_t)M_DIM * H_DIM * 2;
    _Float16* Gz = (_Float16*)ws; ws += (size_t)M_DIM * H_DIM * 2;
    _Float16* Gf = (_Float16*)ws; ws += (size_t)M_DIM * H_DIM * 2;
    _Float16* Go = (_Float16*)ws; ws += (size_t)M_DIM * H_DIM * 2;
    float* cA = (float*)ws;       ws += (size_t)NC * 16384 * 4;
    float* cM = (float*)ws;

    prep_kernel<<<TW_BLOCKS + 16384, 256, 0, stream>>>(W, Wt, x, (const float4*)emb, hbuf);

    for (int l = 0; l < L_DIM; l++) {
        gemm_gates<<<dim3(1536), 512, 0, stream>>>(
            hbuf, Wt + (size_t)l * N_DIM * K_DIM, b + (size_t)l * N_DIM, Gz, Gf, Go);
        int last = (l == L_DIM - 1);
        scan_pass1<<<1024, 256, 0, stream>>>(Gz, Gf, cA, cM);
        scan_prefix<<<16, 256, 0, stream>>>(cA, cM);
        scan_pass23<<<1024, 256, 0, stream>>>(Gz, Gf, Go, cM, hbuf, out, last);
    }
}

// Round 11
// 573.767 us; speedup vs baseline: 1.3044x; 1.3044x over previous
//
#include <hip/hip_runtime.h>
#include <hip/hip_bf16.h>

#define T_DIM 1024
#define B_DIM 16
#define H_DIM 1024
#define L_DIM 3
#define M_DIM (T_DIM * B_DIM)
#define N_DIM (3 * H_DIM)
#define K_DIM H_DIM
#define NC 64
#define CS 16

typedef __bf16 bf16x8 __attribute__((ext_vector_type(8)));
typedef __bf16 bf16x4 __attribute__((ext_vector_type(4)));
typedef _Float16 half4 __attribute__((ext_vector_type(4)));
typedef float f32x4 __attribute__((ext_vector_type(4)));
typedef int int4v __attribute__((ext_vector_type(4)));

__device__ __forceinline__ __bf16 f2bf(float f) {
    return (__bf16)__float2bfloat16(f);
}

__device__ __forceinline__ void async_cp16(const void* g, void* lds) {
    __builtin_amdgcn_global_load_lds(
        (__attribute__((address_space(1))) void*)g,
        (__attribute__((address_space(3))) void*)lds, 16, 0, 0);
}

// ---------- fused prep: W transpose+cast (blocks 0..9215) + embed gather (rest) ----------
#define TW_BLOCKS (32 * 96 * 3)
__global__ void prep_kernel(const float* __restrict__ W, __bf16* __restrict__ Wt,
                            const int* __restrict__ x, const float4* __restrict__ emb,
                            __bf16* __restrict__ h) {
    if (blockIdx.x < TW_BLOCKS) {
        __shared__ __bf16 tile[32][33];
        const int blk = blockIdx.x;
        const int l = blk / 3072;
        const int r2 = blk % 3072;
        const int n0 = (r2 / 32) * 32, k0 = (r2 % 32) * 32;
        const int tx = threadIdx.x & 31, ty = threadIdx.x >> 5;
        const float* Wl = W + (size_t)l * K_DIM * N_DIM;
        __bf16* Wtl = Wt + (size_t)l * N_DIM * K_DIM;
#pragma unroll
        for (int q = 0; q < 4; q++) {
            int k = ty + q * 8;
            tile[k][tx] = f2bf(Wl[(size_t)(k0 + k) * N_DIM + n0 + tx]);
        }
        __syncthreads();
#pragma unroll
        for (int q = 0; q < 4; q++) {
            int n = ty + q * 8;
            Wtl[(size_t)(n0 + n) * K_DIM + k0 + tx] = tile[tx][n];
        }
    } else {
        int i = (blockIdx.x - TW_BLOCKS) * 256 + threadIdx.x;
        int row = i >> 8;
        int j = i & 255;
        int idx = x[row];
        float4 v = emb[(size_t)idx * 256 + j];
        __bf16* dst = h + (size_t)row * H_DIM + j * 4;
        dst[0] = f2bf(v.x); dst[1] = f2bf(v.y); dst[2] = f2bf(v.z); dst[3] = f2bf(v.w);
    }
}

// ---------- GEMM + bias + activation -> fp16 planar gates ----------
// v4 (R9/R10/R11): R5/R7 K-loop (counted-vmcnt depth-2 ring), nt stores REVERTED (R8:
// partial-line nt => HBM RMW, WRITE_SIZE 101->186 MB). LDS-staged epilogue: old epilogue's
// 2 B/lane stores completed each 128-B line across 4 instructions -> L2 write-allocate
// fetched ~84 MB/dispatch of garbage workspace lines (FETCH 122 vs 38 MB ideal).
// Now: stage the 128x256 fp16 tile in LDS (reuse staging buffer, stride 264 halves for
// 16-B alignment), then int4 copy-out: 64 lanes x 16 B = full lines -> allocate-fetch elided.
// Same values, same rounding -> bit-identical output.
__global__ __launch_bounds__(512, 4) void gemm_gates(
    const __bf16* __restrict__ A,
    const __bf16* __restrict__ Wt,
    const float* __restrict__ bias,
    _Float16* __restrict__ Gz, _Float16* __restrict__ Gf, _Float16* __restrict__ Go) {
    __shared__ __align__(16) __bf16 SH[36864];      // 72 KiB: K-loop ring, then out-tile
    __bf16* As = SH;                                // [3][128][32]
    __bf16* Bs = SH + 3 * 4096;                     // [3][256][32]

    const int tid = threadIdx.x;
    const int lane = tid & 63, wid = tid >> 6;
    const int lm = lane & 15, kg = lane >> 4;
    const int wm = wid >> 2, wn = wid & 3;          // 2M x 4N waves of 64x64

    // XCD-bijective swizzle: 1536 blocks, 192/XCD, bm-major chunks (16 bm-panels x 12 bn).
    const int orig = blockIdx.x;                    // 0..1535
    const int lin = (orig & 7) * 192 + (orig >> 3);
    const int bm = lin / 12, bn = lin % 12;

    // staging: A-tile 128x32 (1 load/thread), B-tile 256x32 (2 loads/thread)
    const int arow = tid >> 2;                      // 0..127
    const int asch = (tid & 3) ^ ((arow >> 1) & 3);
    const int gaA = arow * K_DIM + asch * 8;
    const int loA = tid * 8;
    const int brow0 = tid >> 2, brow1 = (512 + tid) >> 2;
    const int bsch0 = (tid & 3) ^ ((brow0 >> 1) & 3);
    const int bsch1 = (tid & 3) ^ ((brow1 >> 1) & 3);
    const int gaB0 = brow0 * K_DIM + bsch0 * 8;
    const int gaB1 = brow1 * K_DIM + bsch1 * 8;
    const int loB0 = tid * 8;
    const int loB1 = (512 + tid) * 8;

    const __bf16* Abase = A + (size_t)(bm * 128) * K_DIM;
    const __bf16* Bbase = Wt + (size_t)(bn * 256) * K_DIM;

    // ds_read fragment offsets (within one region)
    const int slot8 = (kg ^ ((lm >> 1) & 3)) * 8;
    const int a_off0 = (wm * 64 + 0 * 16 + lm) * 32 + slot8;
    const int a_off1 = (wm * 64 + 1 * 16 + lm) * 32 + slot8;
    const int a_off2 = (wm * 64 + 2 * 16 + lm) * 32 + slot8;
    const int a_off3 = (wm * 64 + 3 * 16 + lm) * 32 + slot8;
    const int b_off0 = (wn * 64 + 0 * 16 + lm) * 32 + slot8;
    const int b_off1 = (wn * 64 + 1 * 16 + lm) * 32 + slot8;
    const int b_off2 = (wn * 64 + 2 * 16 + lm) * 32 + slot8;
    const int b_off3 = (wn * 64 + 3 * 16 + lm) * 32 + slot8;

    f32x4 acc[4][4] = {};

#define STAGE(TN) { \
    const int kc_ = ((TN) & 31) * 32; \
    const int rg_ = (TN) % 3; \
    async_cp16(Abase + kc_ + gaA, As + rg_ * 4096 + loA); \
    async_cp16(Bbase + kc_ + gaB0, Bs + rg_ * 8192 + loB0); \
    async_cp16(Bbase + kc_ + gaB1, Bs + rg_ * 8192 + loB1); }

    // prologue: stage tiles 0 and 1 (6 loads outstanding; never drained to 0 in the loop)
    STAGE(0)
    STAGE(1)

#pragma unroll 1
    for (int t = 0; t < 32; ++t) {
        // oldest 3 loads = tile t's stage -> region t%3 ready once ALL waves pass this
        asm volatile("s_waitcnt vmcnt(3)" ::: "memory");
        __builtin_amdgcn_s_barrier();
        __builtin_amdgcn_sched_barrier(0);
        const int rg = t % 3;
        const __bf16* rA = As + rg * 4096;
        const __bf16* rB = Bs + rg * 8192;
        bf16x8 bf0 = *(const bf16x8*)(rB + b_off0);
        bf16x8 bf1 = *(const bf16x8*)(rB + b_off1);
        bf16x8 bf2 = *(const bf16x8*)(rB + b_off2);
        bf16x8 bf3 = *(const bf16x8*)(rB + b_off3);
        bf16x8 af0 = *(const bf16x8*)(rA + a_off0);
        bf16x8 af1 = *(const bf16x8*)(rA + a_off1);
        bf16x8 af2 = *(const bf16x8*)(rA + a_off2);
        bf16x8 af3 = *(const bf16x8*)(rA + a_off3);
        STAGE(t + 2)   // t>=30 wraps to tiles 0/1 (regions differ from t%3,(t+1)%3: safe)
        __builtin_amdgcn_s_setprio(1);
#define MFJ(I, AF) \
        acc[I][0] = __builtin_amdgcn_mfma_f32_16x16x32_bf16(AF, bf0, acc[I][0], 0, 0, 0); \
        acc[I][1] = __builtin_amdgcn_mfma_f32_16x16x32_bf16(AF, bf1, acc[I][1], 0, 0, 0); \
        acc[I][2] = __builtin_amdgcn_mfma_f32_16x16x32_bf16(AF, bf2, acc[I][2], 0, 0, 0); \
        acc[I][3] = __builtin_amdgcn_mfma_f32_16x16x32_bf16(AF, bf3, acc[I][3], 0, 0, 0);
        MFJ(0, af0) MFJ(1, af1) MFJ(2, af2) MFJ(3, af3)
#undef MFJ
        __builtin_amdgcn_s_setprio(0);
    }
    asm volatile("s_waitcnt vmcnt(0)" ::: "memory");

#undef STAGE

    // ---- epilogue: activation -> LDS staging -> full-line coalesced stores ----
    __syncthreads();   // all waves finished ds_reads of the final K-tile before LDS reuse
    _Float16* SHh = (_Float16*)SH;                  // [128][264] fp16, 67584 B <= 73728
    const int plane = bn >> 2;
    _Float16* __restrict__ P = (plane == 0) ? Gz : (plane == 1) ? Gf : Go;
    const int nb = bn * 256 + wn * 64;
#pragma unroll
    for (int i = 0; i < 4; i++) {
#pragma unroll
        for (int j = 0; j < 4; j++) {
            float bv = bias[nb + j * 16 + lm];
#pragma unroll
            for (int r = 0; r < 4; r++) {
                float g = acc[i][j][r] + bv;
                float val;
                if (plane == 0) {
                    // tanh(g) = sign(g) * (1 - 2e/(1+e)), e = exp(-2|g|) <= 1
                    float e = __expf(-2.0f * fabsf(g));
                    float rc = __builtin_amdgcn_rcpf(1.0f + e);
                    val = copysignf(fmaf(-2.0f * e, rc, 1.0f), g);
                } else {
                    float e = __expf(-g);
                    val = __builtin_amdgcn_rcpf(1.0f + e);
                }
                SHh[(wm * 64 + i * 16 + kg * 4 + r) * 264 + wn * 64 + j * 16 + lm]
                    = (_Float16)val;
            }
        }
    }
    __syncthreads();
    {
        const int cb = (bn & 3) * 256;
#pragma unroll
        for (int q = 0; q < 8; q++) {
            int c = q * 512 + tid;                  // 16-B chunk id, 0..4095
            int row = c >> 5, c16 = c & 31;
            int4v v = *(const int4v*)(SHh + row * 264 + c16 * 8);
            *(int4v*)(P + (size_t)(bm * 128 + row) * H_DIM + cb + c16 * 8) = v;
        }
    }
}

// ---------- pass 1: per-chunk affine aggregates ----------
__global__ __launch_bounds__(256, 8) void scan_pass1(
    const _Float16* __restrict__ Gz, const _Float16* __restrict__ Gf,
    float* __restrict__ cA, float* __restrict__ cM) {
    int tidg = blockIdx.x * 256 + threadIdx.x;   // 262144
    int ci = tidg >> 12;
    int chg = tidg & 4095;
    size_t base = (size_t)(ci * CS) * 16384 + (size_t)chg * 4;
    f32x4 Aacc = {0.f, 0.f, 0.f, 0.f};
    f32x4 Macc = {1.f, 1.f, 1.f, 1.f};
#pragma unroll
    for (int s = 0; s < CS; s++) {
        half4 z = *(const half4*)(Gz + base);
        half4 f = *(const half4*)(Gf + base);
#pragma unroll
        for (int k = 0; k < 4; k++) {
            float fk = (float)f[k], zk = (float)z[k];
            Aacc[k] = fk * zk + (1.f - fk) * Aacc[k];
            Macc[k] = (1.f - fk) * Macc[k];
        }
        base += 16384;
    }
    size_t idx = (size_t)ci * 16384 + (size_t)chg * 4;
    *(f32x4*)(cA + idx) = Aacc;
    *(f32x4*)(cM + idx) = Macc;
}

// ---------- pass 1.5: sequential chunk-prefix scan, in-place into cM ----------
// One thread per channel-group (4096 threads). Same fold expression, same cj order as the
// old redundant per-block fold -> bit-identical values. After this kernel,
// cM[cj] holds the running state c ENTERING chunk cj+1 (i.e. prefix over chunks 0..cj).
__global__ __launch_bounds__(256, 8) void scan_prefix(
    const float* __restrict__ cA, float* __restrict__ cM) {
    int chg = blockIdx.x * 256 + threadIdx.x;    // 0..4095
    size_t off = (size_t)chg * 4;
    f32x4 c = {0.f, 0.f, 0.f, 0.f};
#pragma unroll 4
    for (int cj = 0; cj < NC - 1; cj++) {
        f32x4 a = *(const f32x4*)(cA + (size_t)cj * 16384 + off);
        f32x4 m = *(const f32x4*)(cM + (size_t)cj * 16384 + off);
#pragma unroll
        for (int k = 0; k < 4; k++) c[k] = a[k] + m[k] * c[k];
        *(f32x4*)(cM + (size_t)cj * 16384 + off) = c;
    }
}

// ---------- pass 2+3: load chunk-prefix + rescan + o-gate ----------
__global__ __launch_bounds__(256, 8) void scan_pass23(
    const _Float16* __restrict__ Gz, const _Float16* __restrict__ Gf,
    const _Float16* __restrict__ Go,
    const float* __restrict__ cM,
    __bf16* __restrict__ hdst, float* __restrict__ fdst, int is_last) {
    int tidg = blockIdx.x * 256 + threadIdx.x;   // 262144
    int ci = tidg >> 12;                         // uniform per block
    int chg = tidg & 4095;
    // incoming state for this chunk = prefix over chunks 0..ci-1 (precomputed by scan_prefix)
    f32x4 c = {0.f, 0.f, 0.f, 0.f};
    if (ci > 0)
        c = *(const f32x4*)(cM + (size_t)(ci - 1) * 16384 + (size_t)chg * 4);
    size_t p = (size_t)(ci * CS) * 16384 + (size_t)chg * 4;
#pragma unroll
    for (int s = 0; s < CS; s++) {
        int t = ci * CS + s;
        half4 z = *(const half4*)(Gz + p);
        half4 f = *(const half4*)(Gf + p);
        half4 o = *(const half4*)(Go + p);
        f32x4 val;
#pragma unroll
        for (int k = 0; k < 4; k++) {
            float fk = (float)f[k];
            c[k] = fk * (float)z[k] + (1.f - fk) * c[k];
            val[k] = (float)o[k] * c[k];
        }
        if (is_last) {
            if (t < T_DIM - 1)
                *(f32x4*)(fdst + p) = val;
        } else {
            bf16x4 hv;
#pragma unroll
            for (int k = 0; k < 4; k++) hv[k] = f2bf(val[k]);
            *(bf16x4*)(hdst + p) = hv;
        }
        p += 16384;
    }
}

extern "C" void kernel_launch(void* const* d_in, const int* in_sizes, int n_in,
                              void* d_out, int out_size, void* d_ws, size_t ws_size,
                              hipStream_t stream) {
    const int* x = (const int*)d_in[0];
    const float* emb = (const float*)d_in[1];
    const float* W = (const float*)d_in[2];
    const float* b = (const float*)d_in[3];
    float* out = (float*)d_out;

    char* ws = (char*)d_ws;
    size_t need = (size_t)L_DIM * N_DIM * K_DIM * 2
                + (size_t)M_DIM * H_DIM * 2
                + 3ull * M_DIM * H_DIM * 2
                + 2ull * NC * 16384 * 4;
    if (ws_size < need) return;

    __bf16* Wt = (__bf16*)ws;     ws += (size_t)L_DIM * N_DIM * K_DIM * 2;
    __bf16* hbuf = (__bf16*)ws;   ws += (size_t)M_DIM * H_DIM * 2;
    _Float16* Gz = (_Float16*)ws; ws += (size_t)M_DIM * H_DIM * 2;
    _Float16* Gf = (_Float16*)ws; ws += (size_t)M_DIM * H_DIM * 2;
    _Float16* Go = (_Float16*)ws; ws += (size_t)M_DIM * H_DIM * 2;
    float* cA = (float*)ws;       ws += (size_t)NC * 16384 * 4;
    float* cM = (float*)ws;

    prep_kernel<<<TW_BLOCKS + 16384, 256, 0, stream>>>(W, Wt, x, (const float4*)emb, hbuf);

    for (int l = 0; l < L_DIM; l++) {
        gemm_gates<<<dim3(1536), 512, 0, stream>>>(
            hbuf, Wt + (size_t)l * N_DIM * K_DIM, b + (size_t)l * N_DIM, Gz, Gf, Go);
        int last = (l == L_DIM - 1);
        scan_pass1<<<1024, 256, 0, stream>>>(Gz, Gf, cA, cM);
        scan_prefix<<<16, 256, 0, stream>>>(cA, cM);
        scan_pass23<<<1024, 256, 0, stream>>>(Gz, Gf, Go, cM, hbuf, out, last);
    }
}